// Round 2
// baseline (810.206 us; speedup 1.0000x reference)
//
#include <hip/hip_runtime.h>
#include <hip/hip_bf16.h>
#include <float.h>

#define SDIM 192
#define S2 (SDIM*SDIM)        // 36864
#define S3 ((size_t)SDIM*S2)  // 7077888
#define NCH 5
#define RAD 4                 // window 9
#define DCH 48                // d-chunk for fused kernel
#define NDC (SDIM/DCH)        // 4
#define K2THR 128
#define POSBLK (S2/K2THR)     // 288
#define NPART (POSBLK*NDC)    // 1152

__device__ __forceinline__ float bf2f(__hip_bfloat16 x) { return __bfloat162float(x); }

// ---------------- K1: W-axis 9-tap zero-padded sum of the 5 product channels, bf16 out ----------------
__global__ __launch_bounds__(SDIM) void k1_wfilter(const float* __restrict__ pred,
                                                   const float* __restrict__ tgt,
                                                   __hip_bfloat16* __restrict__ A) {
    const int row = blockIdx.x;            // (d*192 + h)
    const int w = threadIdx.x;             // 0..191
    __shared__ float Ir[SDIM];
    __shared__ float Jr[SDIM];
    const size_t base = (size_t)row * SDIM;
    Ir[w] = tgt[base + w];                 // I = target
    Jr[w] = pred[base + w];                // J = pred
    __syncthreads();

    float s0 = 0.f, s1 = 0.f, s2 = 0.f, s3 = 0.f, s4 = 0.f;
#pragma unroll
    for (int dw = -RAD; dw <= RAD; ++dw) {
        const int x = w + dw;
        if (x >= 0 && x < SDIM) {
            const float i = Ir[x];
            const float j = Jr[x];
            s0 += i; s1 += j; s2 += i * i; s3 += j * j; s4 += i * j;
        }
    }
    A[0 * S3 + base + w] = __float2bfloat16(s0);
    A[1 * S3 + base + w] = __float2bfloat16(s1);
    A[2 * S3 + base + w] = __float2bfloat16(s2);
    A[3 * S3 + base + w] = __float2bfloat16(s3);
    A[4 * S3 + base + w] = __float2bfloat16(s4);
}

// ---------------- K2': fused H-filter (9 global rows, L2-served) + D running window (VGPR ring) + cc ----------------
__global__ __launch_bounds__(K2THR) void k2_hd_cc(const __hip_bfloat16* __restrict__ A,
                                                  float* __restrict__ partials) {
    const int bid = blockIdx.x;            // dc*POSBLK + pb
    const int dc = bid / POSBLK;
    const int pb = bid % POSBLK;
    const int pos = pb * K2THR + threadIdx.x;   // (h*192 + w)
    const int h = pos / SDIM;
    const int w = pos % SDIM;
    const int d0 = dc * DCH;

    // per-thread row offsets + validity masks for the 9 H-taps (static-indexed)
    int off[9];
    float msk[9];
#pragma unroll
    for (int dh = 0; dh < 9; ++dh) {
        const int hh = h + dh - RAD;
        const int hc = hh < 0 ? 0 : (hh > SDIM - 1 ? SDIM - 1 : hh);
        off[dh] = hc * SDIM + w;
        msk[dh] = (hh >= 0 && hh < SDIM) ? 1.0f : 0.0f;
    }

    float ring[NCH][9];                    // statically-indexed VGPR ring of H-filtered slices
    float z[NCH];
#pragma unroll
    for (int c = 0; c < NCH; ++c) {
        z[c] = 0.f;
#pragma unroll
        for (int k = 0; k < 9; ++k) ring[c][k] = 0.f;
    }

    const float inv = 1.0f / 729.0f;
    const float eps = 1.1920929e-07f;      // np.finfo(float32).eps
    float acc = 0.f;

    const int NSTEP = DCH + 2 * RAD;       // 56
    for (int so = 0; so < 63; so += 9) {   // 9-unrolled so ring slot == k (compile-time)
#pragma unroll
        for (int k = 0; k < 9; ++k) {
            const int step = so + k;
            if (step < NSTEP) {
                const int s = d0 - RAD + step;
                float hfil[NCH] = {0.f, 0.f, 0.f, 0.f, 0.f};
                if (s >= 0 && s < SDIM) {
                    const size_t sbase = (size_t)s * S2;
#pragma unroll
                    for (int c = 0; c < NCH; ++c) {
                        const __hip_bfloat16* __restrict__ Ac = A + (size_t)c * S3 + sbase;
                        float f = 0.f;
#pragma unroll
                        for (int dh = 0; dh < 9; ++dh)
                            f += bf2f(Ac[off[dh]]) * msk[dh];
                        hfil[c] = f;
                    }
                }
#pragma unroll
                for (int c = 0; c < NCH; ++c) {
                    z[c] -= ring[c][k];    // value from slice s-9 (0 if never filled)
                    ring[c][k] = hfil[c];
                    z[c] += hfil[c];
                }
                if (s >= d0 + RAD) {       // emit output d = s - 4
                    const float mu1 = z[0] * inv;
                    const float mu2 = z[1] * inv;
                    const float cI2 = z[2] * inv;
                    const float cJ2 = z[3] * inv;
                    const float cIJ = z[4] * inv;
                    const float sg1 = cI2 - mu1 * mu1;
                    const float sg2 = cJ2 - mu2 * mu2;
                    const float s12 = cIJ - mu1 * mu2;
                    acc += (s12 * s12) / (sg1 * sg2 + eps);
                }
            }
        }
    }

    __shared__ float red[K2THR];
    red[threadIdx.x] = acc;
    __syncthreads();
#pragma unroll
    for (int o = K2THR / 2; o > 0; o >>= 1) {
        if (threadIdx.x < o) red[threadIdx.x] += red[threadIdx.x + o];
        __syncthreads();
    }
    if (threadIdx.x == 0) partials[bid] = red[0];
}

// ---------------- K4: final deterministic reduction ----------------
__global__ __launch_bounds__(256) void k4_finalize(const float* __restrict__ partials,
                                                   float* __restrict__ out) {
    __shared__ float sm[256];
    float s = 0.f;
    for (int i = threadIdx.x; i < NPART; i += 256) s += partials[i];
    sm[threadIdx.x] = s;
    __syncthreads();
#pragma unroll
    for (int o = 128; o > 0; o >>= 1) {
        if (threadIdx.x < o) sm[threadIdx.x] += sm[threadIdx.x + o];
        __syncthreads();
    }
    if (threadIdx.x == 0) out[0] = 1.0f - sm[0] / (float)((size_t)SDIM * S2);
}

extern "C" void kernel_launch(void* const* d_in, const int* in_sizes, int n_in,
                              void* d_out, int out_size, void* d_ws, size_t ws_size,
                              hipStream_t stream) {
    const float* pred = (const float*)d_in[0];
    const float* tgt  = (const float*)d_in[1];
    float* out = (float*)d_out;

    const size_t a_bf = (size_t)NCH * S3 * sizeof(__hip_bfloat16);   // ~70.8 MB
    const size_t a_bf_pad = (a_bf + 255) & ~(size_t)255;

    __hip_bfloat16* A = (__hip_bfloat16*)d_ws;
    float* partials = (float*)((char*)d_ws + a_bf_pad);

    k1_wfilter<<<S2, SDIM, 0, stream>>>(pred, tgt, A);
    k2_hd_cc<<<NPART, K2THR, 0, stream>>>(A, partials);
    k4_finalize<<<1, 256, 0, stream>>>(partials, out);
}

// Round 3
// 186.354 us; speedup vs baseline: 4.3477x; 4.3477x over previous
//
#include <hip/hip_runtime.h>
#include <hip/hip_bf16.h>
#include <float.h>

#define SDIM 192
#define S2 (SDIM*SDIM)        // 36864
#define S3 ((size_t)SDIM*S2)  // 7077888
#define NCH 5
#define RAD 4                 // window 9

// KA tiling
#define TILE 32
#define RTILE (TILE + 2*RAD)  // 40
#define RPAD 44               // padded raw row (f32) — conflict-free
#define WPAD 33               // padded wfil row (bf16)
#define NTIL (SDIM/TILE)      // 6

// KB tiling
#define DCH 24
#define NDC (SDIM/DCH)        // 8
#define NSTEP (DCH + 2*RAD)   // 32
#define POSB (S2/256)         // 144
#define NPART (POSB*NDC)      // 1152

__device__ __forceinline__ float bf2f(__hip_bfloat16 x) { return __bfloat162float(x); }
__device__ __forceinline__ __hip_bfloat16 f2bf(float x) { return __float2bfloat16(x); }

// ---------------- KA: W + H 9-tap (zero-padded) of the 5 product channels, per d-slice tile ----------------
__global__ __launch_bounds__(256) void ka_wh(const float* __restrict__ pred,
                                             const float* __restrict__ tgt,
                                             __hip_bfloat16* __restrict__ B) {
    const int b = blockIdx.x;              // d*36 + ty*6 + tx
    const int tx = b % NTIL;
    const int ty = (b / NTIL) % NTIL;
    const int d = b / (NTIL * NTIL);
    const int h0 = ty * TILE, w0 = tx * TILE;
    const size_t dbase = (size_t)d * S2;

    __shared__ float Ir[RTILE][RPAD];
    __shared__ float Jr[RTILE][RPAD];
    __shared__ __hip_bfloat16 wf[NCH][RTILE][WPAD];

    // stage raw halo tile (zero-padded outside volume)
    for (int idx = threadIdx.x; idx < RTILE * RTILE; idx += 256) {
        const int r = idx / RTILE, c = idx % RTILE;
        const int hh = h0 - RAD + r, ww = w0 - RAD + c;
        const bool ok = (hh >= 0 && hh < SDIM && ww >= 0 && ww < SDIM);
        const size_t g = dbase + (size_t)hh * SDIM + ww;
        Ir[r][c] = ok ? tgt[g] : 0.f;
        Jr[r][c] = ok ? pred[g] : 0.f;
    }
    __syncthreads();

    // W filter over all RTILE rows (incl. h-halo), TILE output cols
    for (int idx = threadIdx.x; idx < RTILE * TILE; idx += 256) {
        const int r = idx / TILE, cr = idx % TILE;
        float s0 = 0.f, s1 = 0.f, s2 = 0.f, s3 = 0.f, s4 = 0.f;
#pragma unroll
        for (int dw = 0; dw < 9; ++dw) {
            const float i = Ir[r][cr + dw];
            const float j = Jr[r][cr + dw];
            s0 += i; s1 += j; s2 += i * i; s3 += j * j; s4 += i * j;
        }
        wf[0][r][cr] = f2bf(s0);
        wf[1][r][cr] = f2bf(s1);
        wf[2][r][cr] = f2bf(s2);
        wf[3][r][cr] = f2bf(s3);
        wf[4][r][cr] = f2bf(s4);
    }
    __syncthreads();

    // H filter + store bf16
    for (int idx = threadIdx.x; idx < NCH * TILE * TILE; idx += 256) {
        const int c = idx / (TILE * TILE);
        const int rem = idx % (TILE * TILE);
        const int hr = rem / TILE, wr = rem % TILE;
        float s = 0.f;
#pragma unroll
        for (int dh = 0; dh < 9; ++dh) s += bf2f(wf[c][hr + dh][wr]);
        B[(size_t)c * S3 + dbase + (size_t)(h0 + hr) * SDIM + (w0 + wr)] = f2bf(s);
    }
}

// ---------------- KB: D-axis running window (static VGPR ring) + cc + deterministic reduction ----------------
__global__ __launch_bounds__(256) void kb_d_cc(const __hip_bfloat16* __restrict__ B,
                                               float* __restrict__ partials) {
    const int bid = blockIdx.x;            // dc*POSB + pb
    const int dc = bid / POSB;
    const int pb = bid % POSB;
    const int pos = pb * 256 + threadIdx.x;   // (h*192 + w)
    const int d0 = dc * DCH;

    float ring[NCH][9];
    float z[NCH];
#pragma unroll
    for (int c = 0; c < NCH; ++c) {
        z[c] = 0.f;
#pragma unroll
        for (int k = 0; k < 9; ++k) ring[c][k] = 0.f;
    }

    const float inv = 1.0f / 729.0f;
    const float eps = 1.1920929e-07f;      // np.finfo(float32).eps
    float acc = 0.f;

    for (int so = 0; so < 36; so += 9) {   // 9-unrolled: ring slot == k at compile time
#pragma unroll
        for (int k = 0; k < 9; ++k) {
            const int step = so + k;
            if (step < NSTEP) {
                const int s = d0 - RAD + step;
                const bool ok = (s >= 0 && s < SDIM);
                const size_t sb = ok ? ((size_t)s * S2 + pos) : 0;
                float v[NCH];
#pragma unroll
                for (int c = 0; c < NCH; ++c) {
                    v[c] = ok ? bf2f(B[(size_t)c * S3 + sb]) : 0.f;
                    z[c] -= ring[c][k];
                    ring[c][k] = v[c];
                    z[c] += v[c];
                }
                if (step >= 2 * RAD) {     // emit output d = s - 4
                    const float mu1 = z[0] * inv;
                    const float mu2 = z[1] * inv;
                    const float cI2 = z[2] * inv;
                    const float cJ2 = z[3] * inv;
                    const float cIJ = z[4] * inv;
                    const float sg1 = cI2 - mu1 * mu1;
                    const float sg2 = cJ2 - mu2 * mu2;
                    const float s12 = cIJ - mu1 * mu2;
                    acc += (s12 * s12) / (sg1 * sg2 + eps);
                }
            }
        }
    }

    __shared__ float red[256];
    red[threadIdx.x] = acc;
    __syncthreads();
#pragma unroll
    for (int o = 128; o > 0; o >>= 1) {
        if (threadIdx.x < o) red[threadIdx.x] += red[threadIdx.x + o];
        __syncthreads();
    }
    if (threadIdx.x == 0) partials[bid] = red[0];
}

// ---------------- K4: final deterministic reduction ----------------
__global__ __launch_bounds__(256) void k4_finalize(const float* __restrict__ partials,
                                                   float* __restrict__ out) {
    __shared__ float sm[256];
    float s = 0.f;
    for (int i = threadIdx.x; i < NPART; i += 256) s += partials[i];
    sm[threadIdx.x] = s;
    __syncthreads();
#pragma unroll
    for (int o = 128; o > 0; o >>= 1) {
        if (threadIdx.x < o) sm[threadIdx.x] += sm[threadIdx.x + o];
        __syncthreads();
    }
    if (threadIdx.x == 0) out[0] = 1.0f - sm[0] / (float)((size_t)SDIM * S2);
}

extern "C" void kernel_launch(void* const* d_in, const int* in_sizes, int n_in,
                              void* d_out, int out_size, void* d_ws, size_t ws_size,
                              hipStream_t stream) {
    const float* pred = (const float*)d_in[0];
    const float* tgt  = (const float*)d_in[1];
    float* out = (float*)d_out;

    const size_t b_bytes = (size_t)NCH * S3 * sizeof(__hip_bfloat16);   // ~70.8 MB
    const size_t b_pad = (b_bytes + 255) & ~(size_t)255;

    __hip_bfloat16* B = (__hip_bfloat16*)d_ws;
    float* partials = (float*)((char*)d_ws + b_pad);

    ka_wh<<<SDIM * NTIL * NTIL, 256, 0, stream>>>(pred, tgt, B);
    kb_d_cc<<<NPART, 256, 0, stream>>>(B, partials);
    k4_finalize<<<1, 256, 0, stream>>>(partials, out);
}

// Round 4
// 103.347 us; speedup vs baseline: 7.8397x; 1.8032x over previous
//
#include <hip/hip_runtime.h>
#include <hip/hip_bf16.h>

#define SDIM 192
#define S2 (SDIM*SDIM)        // 36864
#define S3 ((size_t)SDIM*S2)  // 7077888
#define NCH 5
#define RAD 4                 // window 9

// ---- KA tiling: one d-slice, 8 output rows, full 192-w strip per block ----
#define STRH 8
#define RROW 16               // staged rows (8 + 2*4 halo)
#define RSTR 200              // f32 LDS row stride (192 + 2*4 zero pad), 16B-aligned rows
#define WSTR 97               // uint (bf16x2) stride per wf row
#define NSTRIP (SDIM/STRH)    // 24

// ---- KB tiling ----
#define KBC 4                               // w-positions per thread (one uint2 = 4 bf16)
#define KB_POSB (S2/(256*KBC))              // 36 position-blocks
#define KB_DCH 8
#define KB_NDC (SDIM/KB_DCH)                // 24
#define KB_GRID (KB_POSB*KB_NDC)            // 864
#define NPART KB_GRID

__device__ __forceinline__ unsigned short f2bfu(float x) {
    __hip_bfloat16 h = __float2bfloat16(x);
    unsigned short u; __builtin_memcpy(&u, &h, 2); return u;
}

// 9-tap sliding sum over pv[0..10] -> 3 outputs, packed into LDS as bf16
__device__ __forceinline__ void store3(unsigned short* wf16, int cidx, int row, int c0,
                                       const float* pv) {
    float s = 0.f;
#pragma unroll
    for (int k = 0; k < 9; ++k) s += pv[k];
    const float o1 = s - pv[0] + pv[9];
    const float o2 = o1 - pv[1] + pv[10];
    const int base = (cidx * RROW + row) * (2 * WSTR) + c0;
    wf16[base + 0] = f2bfu(s);
    wf16[base + 1] = f2bfu(o1);
    wf16[base + 2] = f2bfu(o2);
}

// ---------------- KA: W + H 9-tap (zero-padded) of the 5 product channels ----------------
__global__ __launch_bounds__(256) void ka_wh(const float* __restrict__ pred,
                                             const float* __restrict__ tgt,
                                             unsigned* __restrict__ BU) {
    const int b = blockIdx.x;              // d*24 + strip
    const int strip = b % NSTRIP;
    const int d = b / NSTRIP;
    const int h0 = strip * STRH;
    const size_t dbase = (size_t)d * S2;
    const int t = threadIdx.x;

    __shared__ float Ir[RROW][RSTR];
    __shared__ float Jr[RROW][RSTR];
    __shared__ unsigned wfU[NCH][RROW][WSTR];   // bf16x2 packed

    // zero the 4-col pads on both w-edges
    for (int u = t; u < RROW * 8; u += 256) {
        const int r = u / 8, p = u % 8;
        const int col = (p < 4) ? p : (192 + p);   // 0..3 / 196..199
        Ir[r][col] = 0.f; Jr[r][col] = 0.f;
    }
    // stage interior rows as float4 (zero rows outside volume)
    const float4* tg4 = (const float4*)tgt;
    const float4* pr4 = (const float4*)pred;
    for (int u = t; u < RROW * 48; u += 256) {
        const int r = u / 48, q = u % 48;
        const int hh = h0 - RAD + r;
        float4 vi = make_float4(0.f, 0.f, 0.f, 0.f), vj = vi;
        if (hh >= 0 && hh < SDIM) {
            const size_t gi = (dbase + (size_t)hh * SDIM) / 4 + q;
            vi = tg4[gi]; vj = pr4[gi];
        }
        *(float4*)&Ir[r][4 + q * 4] = vi;
        *(float4*)&Jr[r][4 + q * 4] = vj;
    }
    __syncthreads();

    // W phase: each wave owns a row (iterating 4 rows); lane owns 3 consecutive cols.
    unsigned short* wf16 = (unsigned short*)wfU;
    const int wv = t >> 6, lane = t & 63;
    const int c0 = lane * 3;               // output cols c0..c0+2
    for (int row = wv; row < RROW; row += 4) {
        float fi[11], fj[11];
#pragma unroll
        for (int k = 0; k < 11; ++k) { fi[k] = Ir[row][c0 + k]; fj[k] = Jr[row][c0 + k]; }
        float pv[11];
#pragma unroll
        for (int k = 0; k < 11; ++k) pv[k] = fi[k];
        store3(wf16, 0, row, c0, pv);
#pragma unroll
        for (int k = 0; k < 11; ++k) pv[k] = fj[k];
        store3(wf16, 1, row, c0, pv);
#pragma unroll
        for (int k = 0; k < 11; ++k) pv[k] = fi[k] * fi[k];
        store3(wf16, 2, row, c0, pv);
#pragma unroll
        for (int k = 0; k < 11; ++k) pv[k] = fj[k] * fj[k];
        store3(wf16, 3, row, c0, pv);
#pragma unroll
        for (int k = 0; k < 11; ++k) pv[k] = fi[k] * fj[k];
        store3(wf16, 4, row, c0, pv);
    }
    __syncthreads();

    // H phase: 8 rows x 96 w-pairs = 768 units, 3 per thread; packed uint loads/stores.
#pragma unroll
    for (int i = 0; i < 3; ++i) {
        const int u = t + 256 * i;
        const int hr = u / 96, wp = u % 96;
#pragma unroll
        for (int c = 0; c < NCH; ++c) {
            float lo = 0.f, hi = 0.f;
#pragma unroll
            for (int dh = 0; dh < 9; ++dh) {
                const unsigned v = wfU[c][hr + dh][wp];
                lo += __uint_as_float(v << 16);
                hi += __uint_as_float(v & 0xffff0000u);
            }
            const unsigned out = (unsigned)f2bfu(lo) | ((unsigned)f2bfu(hi) << 16);
            BU[(size_t)c * (S3 / 2) + (dbase + (size_t)(h0 + hr) * SDIM) / 2 + wp] = out;
        }
    }
}

// ---------------- KB: D-axis sliding window (add/sub, uint2 loads) + cc + reduce ----------------
#define SLICE_OP(s, OP) { const size_t sb = ((size_t)(s) * S2 + pos0) / 4; \
    _Pragma("unroll") for (int c = 0; c < NCH; ++c) { \
        const uint2 v = B2[(size_t)c * (S3 / 4) + sb]; \
        z[c][0] OP __uint_as_float(v.x << 16); \
        z[c][1] OP __uint_as_float(v.x & 0xffff0000u); \
        z[c][2] OP __uint_as_float(v.y << 16); \
        z[c][3] OP __uint_as_float(v.y & 0xffff0000u); } }

__global__ __launch_bounds__(256) void kb_d_cc(const unsigned* __restrict__ BU,
                                               float* __restrict__ partials) {
    const int bid = blockIdx.x;
    const int dc = bid / KB_POSB;
    const int pb = bid % KB_POSB;
    const int d0 = dc * KB_DCH;
    const int pos0 = pb * (256 * KBC) + threadIdx.x * KBC;
    const uint2* B2 = (const uint2*)BU;

    float z[NCH][KBC];
#pragma unroll
    for (int c = 0; c < NCH; ++c)
#pragma unroll
        for (int i = 0; i < KBC; ++i) z[c][i] = 0.f;

    // warm up: window for output d0 (slices d0-4..d0+4, zero-padded)
#pragma unroll
    for (int dd = -RAD; dd <= RAD; ++dd) {
        const int s = d0 + dd;
        if (s >= 0 && s < SDIM) SLICE_OP(s, +=)
    }

    const float inv = 1.0f / 729.0f;
    const float eps = 1.1920929e-07f;      // np.finfo(float32).eps
    float acc = 0.f;

#pragma unroll
    for (int k = 0; k < KB_DCH; ++k) {
        const int d = d0 + k;
#pragma unroll
        for (int i = 0; i < KBC; ++i) {
            const float mu1 = z[0][i] * inv;
            const float mu2 = z[1][i] * inv;
            const float sg1 = z[2][i] * inv - mu1 * mu1;
            const float sg2 = z[3][i] * inv - mu2 * mu2;
            const float s12 = z[4][i] * inv - mu1 * mu2;
            acc += (s12 * s12) / (sg1 * sg2 + eps);
        }
        const int da = d + RAD + 1;
        const int ds = d - RAD;
        if (da < SDIM) SLICE_OP(da, +=)
        if (ds >= 0)   SLICE_OP(ds, -=)
    }

    __shared__ float red[256];
    red[threadIdx.x] = acc;
    __syncthreads();
#pragma unroll
    for (int o = 128; o > 0; o >>= 1) {
        if (threadIdx.x < o) red[threadIdx.x] += red[threadIdx.x + o];
        __syncthreads();
    }
    if (threadIdx.x == 0) partials[bid] = red[0];
}

// ---------------- K4: final deterministic reduction ----------------
__global__ __launch_bounds__(256) void k4_finalize(const float* __restrict__ partials,
                                                   float* __restrict__ out) {
    __shared__ float sm[256];
    float s = 0.f;
    for (int i = threadIdx.x; i < NPART; i += 256) s += partials[i];
    sm[threadIdx.x] = s;
    __syncthreads();
#pragma unroll
    for (int o = 128; o > 0; o >>= 1) {
        if (threadIdx.x < o) sm[threadIdx.x] += sm[threadIdx.x + o];
        __syncthreads();
    }
    if (threadIdx.x == 0) out[0] = 1.0f - sm[0] / (float)((size_t)SDIM * S2);
}

extern "C" void kernel_launch(void* const* d_in, const int* in_sizes, int n_in,
                              void* d_out, int out_size, void* d_ws, size_t ws_size,
                              hipStream_t stream) {
    const float* pred = (const float*)d_in[0];
    const float* tgt  = (const float*)d_in[1];
    float* out = (float*)d_out;

    const size_t b_bytes = (size_t)NCH * S3 * sizeof(__hip_bfloat16);   // ~70.8 MB
    const size_t b_pad = (b_bytes + 255) & ~(size_t)255;

    unsigned* BU = (unsigned*)d_ws;
    float* partials = (float*)((char*)d_ws + b_pad);

    ka_wh<<<SDIM * NSTRIP, 256, 0, stream>>>(pred, tgt, BU);
    kb_d_cc<<<KB_GRID, 256, 0, stream>>>(BU, partials);
    k4_finalize<<<1, 256, 0, stream>>>(partials, out);
}

// Round 6
// 95.275 us; speedup vs baseline: 8.5038x; 1.0847x over previous
//
#include <hip/hip_runtime.h>
#include <hip/hip_bf16.h>

#define SDIM 192
#define S2 (SDIM*SDIM)        // 36864
#define S3 ((size_t)SDIM*S2)  // 7077888
#define NCH 5
#define RAD 4                 // window 9

// ---- KA: one d-slice, 8 output rows, full 192-w strip per block ----
#define STRH 8
#define RROW 16               // staged rows (8 + 2*4 halo)
#define RST 200               // uint stride per raw row: packed {i,j} bf16, 4+192+4 cols
#define WSTR 97               // uint (bf16x2) stride per wf row
#define NSTRIP (SDIM/STRH)    // 24

// ---- KB: D-axis via 9-slot register ring, each slice read once ----
#define KB_KBC 2                            // w-positions per thread (one uint = 2 bf16)
#define KB_POSB (S2/(256*KB_KBC))           // 72
#define KB_DCH 16
#define KB_NDC (SDIM/KB_DCH)                // 12
#define KB_GRID (KB_POSB*KB_NDC)            // 864
#define KB_NSTEP (KB_DCH + 2*RAD)           // 24
#define NPART KB_GRID

__device__ __forceinline__ unsigned short f2bfu(float x) {
    __hip_bfloat16 h = __float2bfloat16(x);
    unsigned short u; __builtin_memcpy(&u, &h, 2); return u;
}
__device__ __forceinline__ unsigned packbf(float lo, float hi) {
    return (unsigned)f2bfu(lo) | ((unsigned)f2bfu(hi) << 16);
}
__device__ __forceinline__ float ulo(unsigned u) { return __uint_as_float(u << 16); }
__device__ __forceinline__ float uhi(unsigned u) { return __uint_as_float(u & 0xffff0000u); }

// 9-tap sliding sum over pv[0..10] -> 3 bf16 outputs into LDS
__device__ __forceinline__ void store3(unsigned short* wf16, int cidx, int row, int c0,
                                       const float* pv) {
    float s = 0.f;
#pragma unroll
    for (int k = 0; k < 9; ++k) s += pv[k];
    const float o1 = s - pv[0] + pv[9];
    const float o2 = o1 - pv[1] + pv[10];
    const int base = (cidx * RROW + row) * (2 * WSTR) + c0;
    wf16[base + 0] = f2bfu(s);
    wf16[base + 1] = f2bfu(o1);
    wf16[base + 2] = f2bfu(o2);
}

// ---------------- KA: W + H 9-tap (zero-padded) of the 5 product channels ----------------
__global__ __launch_bounds__(256) void ka_wh(const float* __restrict__ pred,
                                             const float* __restrict__ tgt,
                                             unsigned* __restrict__ BU) {
    const int b = blockIdx.x;              // d*24 + strip
    const int strip = b % NSTRIP;
    const int d = b / NSTRIP;
    const int h0 = strip * STRH;
    const size_t dbase = (size_t)d * S2;
    const int t = threadIdx.x;

    __shared__ unsigned IJ[RROW][RST];          // packed {i(lo), j(hi)} bf16 — 12.8 KB
    __shared__ unsigned wfU[NCH][RROW][WSTR];   // bf16x2 over w — 31.0 KB

    // zero the 4-col pads on both w-edges: cols 0..3 and 196..199 (one uint per col!)
    if (t < RROW * 8) {
        const int r = t >> 3, p = t & 7;
        const int col = (p < 4) ? p : (192 + p);   // 0..3 / 196..199
        IJ[r][col] = 0u;
    }
    // stage interior rows: float4 global loads -> packed bf16{i,j} uint4 LDS writes
    const float4* tg4 = (const float4*)tgt;
    const float4* pr4 = (const float4*)pred;
#pragma unroll
    for (int it = 0; it < 3; ++it) {
        const int u = t + 256 * it;            // 0..767
        const int r = u / 48, q = u % 48;
        const int hh = h0 - RAD + r;
        float4 vi = make_float4(0.f, 0.f, 0.f, 0.f), vj = vi;
        if (hh >= 0 && hh < SDIM) {
            const size_t gi = (dbase + (size_t)hh * SDIM) / 4 + q;
            vi = tg4[gi]; vj = pr4[gi];
        }
        uint4 w;
        w.x = packbf(vi.x, vj.x); w.y = packbf(vi.y, vj.y);
        w.z = packbf(vi.z, vj.z); w.w = packbf(vi.w, vj.w);
        *(uint4*)&IJ[r][4 + 4 * q] = w;
    }
    __syncthreads();

    // W phase: wave owns rows wv, wv+4, wv+8, wv+12; lane owns 3 consecutive output cols.
    unsigned short* wf16 = (unsigned short*)wfU;
    const int wv = t >> 6, lane = t & 63;
    const int c0 = lane * 3;
#pragma unroll
    for (int rr = 0; rr < 4; ++rr) {
        const int row = wv + rr * 4;
        float fi[11], fj[11];
#pragma unroll
        for (int k = 0; k < 11; ++k) {
            const unsigned u = IJ[row][c0 + k];
            fi[k] = ulo(u); fj[k] = uhi(u);
        }
        float pv[11];
#pragma unroll
        for (int k = 0; k < 11; ++k) pv[k] = fi[k];
        store3(wf16, 0, row, c0, pv);
#pragma unroll
        for (int k = 0; k < 11; ++k) pv[k] = fj[k];
        store3(wf16, 1, row, c0, pv);
#pragma unroll
        for (int k = 0; k < 11; ++k) pv[k] = fi[k] * fi[k];
        store3(wf16, 2, row, c0, pv);
#pragma unroll
        for (int k = 0; k < 11; ++k) pv[k] = fj[k] * fj[k];
        store3(wf16, 3, row, c0, pv);
#pragma unroll
        for (int k = 0; k < 11; ++k) pv[k] = fi[k] * fj[k];
        store3(wf16, 4, row, c0, pv);
    }
    __syncthreads();

    // H phase: thread owns a (channel, w-pair) column; sliding 9-sum over h, 8 outputs.
#pragma unroll
    for (int it = 0; it < 2; ++it) {
        const int col = t + 256 * it;          // 0..479 = c*96 + wp
        if (col < NCH * 96) {
            const int c = col / 96, wp = col % 96;
            float lo[RROW], hi[RROW];
#pragma unroll
            for (int r = 0; r < RROW; ++r) {
                const unsigned v = wfU[c][r][wp];
                lo[r] = ulo(v); hi[r] = uhi(v);
            }
            float slo = 0.f, shi = 0.f;
#pragma unroll
            for (int r = 0; r < 9; ++r) { slo += lo[r]; shi += hi[r]; }
            unsigned* dst = BU + (size_t)c * (S3 / 2) + (dbase + (size_t)h0 * SDIM) / 2 + wp;
            dst[0] = packbf(slo, shi);
#pragma unroll
            for (int hr = 1; hr < STRH; ++hr) {
                slo += lo[hr + 8] - lo[hr - 1];
                shi += hi[hr + 8] - hi[hr - 1];
                dst[hr * (SDIM / 2)] = packbf(slo, shi);
            }
        }
    }
}

// ---------------- KB: D-axis 9-slot register ring (each slice read once) + cc + reduce ----------------
__global__ __launch_bounds__(256) void kb_d_cc(const unsigned* __restrict__ BU,
                                               float* __restrict__ partials) {
    const int bid = blockIdx.x;
    const int dc = bid / KB_POSB;
    const int pb = bid % KB_POSB;
    const int d0 = dc * KB_DCH;
    const int pos0 = pb * (256 * KB_KBC) + threadIdx.x * KB_KBC;

    float ring[NCH][9][KB_KBC];
    float z[NCH][KB_KBC];
#pragma unroll
    for (int c = 0; c < NCH; ++c) {
#pragma unroll
        for (int i = 0; i < KB_KBC; ++i) z[c][i] = 0.f;
#pragma unroll
        for (int k = 0; k < 9; ++k)
#pragma unroll
            for (int i = 0; i < KB_KBC; ++i) ring[c][k][i] = 0.f;
    }

    const float inv = 1.0f / 729.0f;
    const float eps = 1.1920929e-07f;      // np.finfo(float32).eps
    float acc = 0.f;

#pragma unroll
    for (int so = 0; so < 27; so += 9) {   // 9-unrolled: ring slot == k at compile time
#pragma unroll
        for (int k = 0; k < 9; ++k) {
            const int step = so + k;
            if (step < KB_NSTEP) {
                const int s = d0 - RAD + step;
                float v[NCH][KB_KBC];
                if (s >= 0 && s < SDIM) {  // wave-uniform branch
                    const size_t sb = ((size_t)s * S2 + pos0) >> 1;
#pragma unroll
                    for (int c = 0; c < NCH; ++c) {
                        const unsigned u = BU[(size_t)c * (S3 >> 1) + sb];
                        v[c][0] = ulo(u); v[c][1] = uhi(u);
                    }
                } else {
#pragma unroll
                    for (int c = 0; c < NCH; ++c) { v[c][0] = 0.f; v[c][1] = 0.f; }
                }
#pragma unroll
                for (int c = 0; c < NCH; ++c)
#pragma unroll
                    for (int i = 0; i < KB_KBC; ++i) {
                        z[c][i] += v[c][i] - ring[c][k][i];
                        ring[c][k][i] = v[c][i];
                    }
                if (step >= 2 * RAD) {     // emit output d = s - 4
#pragma unroll
                    for (int i = 0; i < KB_KBC; ++i) {
                        const float mu1 = z[0][i] * inv;
                        const float mu2 = z[1][i] * inv;
                        const float sg1 = z[2][i] * inv - mu1 * mu1;
                        const float sg2 = z[3][i] * inv - mu2 * mu2;
                        const float s12 = z[4][i] * inv - mu1 * mu2;
                        acc += (s12 * s12) / (sg1 * sg2 + eps);
                    }
                }
            }
        }
    }

    __shared__ float red[256];
    red[threadIdx.x] = acc;
    __syncthreads();
#pragma unroll
    for (int o = 128; o > 0; o >>= 1) {
        if (threadIdx.x < o) red[threadIdx.x] += red[threadIdx.x + o];
        __syncthreads();
    }
    if (threadIdx.x == 0) partials[bid] = red[0];
}

// ---------------- K4: final deterministic reduction ----------------
__global__ __launch_bounds__(256) void k4_finalize(const float* __restrict__ partials,
                                                   float* __restrict__ out) {
    __shared__ float sm[256];
    float s = 0.f;
    for (int i = threadIdx.x; i < NPART; i += 256) s += partials[i];
    sm[threadIdx.x] = s;
    __syncthreads();
#pragma unroll
    for (int o = 128; o > 0; o >>= 1) {
        if (threadIdx.x < o) sm[threadIdx.x] += sm[threadIdx.x + o];
        __syncthreads();
    }
    if (threadIdx.x == 0) out[0] = 1.0f - sm[0] / (float)((size_t)SDIM * S2);
}

extern "C" void kernel_launch(void* const* d_in, const int* in_sizes, int n_in,
                              void* d_out, int out_size, void* d_ws, size_t ws_size,
                              hipStream_t stream) {
    const float* pred = (const float*)d_in[0];
    const float* tgt  = (const float*)d_in[1];
    float* out = (float*)d_out;

    const size_t b_bytes = (size_t)NCH * S3 * sizeof(__hip_bfloat16);   // ~70.8 MB
    const size_t b_pad = (b_bytes + 255) & ~(size_t)255;

    unsigned* BU = (unsigned*)d_ws;
    float* partials = (float*)((char*)d_ws + b_pad);

    ka_wh<<<SDIM * NSTRIP, 256, 0, stream>>>(pred, tgt, BU);
    kb_d_cc<<<KB_GRID, 256, 0, stream>>>(BU, partials);
    k4_finalize<<<1, 256, 0, stream>>>(partials, out);
}

// Round 7
// 84.342 us; speedup vs baseline: 9.6062x; 1.1296x over previous
//
#include <hip/hip_runtime.h>
#include <hip/hip_bf16.h>

#define SDIM 192
#define S2 (SDIM*SDIM)        // 36864
#define S3 ((size_t)SDIM*S2)  // 7077888
#define NCH 5
#define RAD 4                 // window 9

// ---- KA: one d-slice, 8 output rows, full 192-w strip per block ----
#define STRH 8
#define RROW 16               // staged rows (8 + 2*4 halo)
#define RST 200               // uint stride per raw row: packed {i,j} bf16, 4+192+4 cols
#define WSTR 97               // uint (bf16x2) stride per wf row
#define NSTRIP (SDIM/STRH)    // 24

// ---- KB: D-axis add/sub sliding window, uint4 (8 bf16) per thread ----
#define KB_KBC 8                            // w-positions per thread (one uint4 = 8 bf16)
#define KB_POSB (S2/(256*KB_KBC))           // 18
#define KB_DCH 8
#define KB_NDC (SDIM/KB_DCH)                // 24
#define KB_GRID (KB_POSB*KB_NDC)            // 432
#define NPART KB_GRID

__device__ __forceinline__ unsigned short f2bfu(float x) {
    __hip_bfloat16 h = __float2bfloat16(x);
    unsigned short u; __builtin_memcpy(&u, &h, 2); return u;
}
__device__ __forceinline__ unsigned packbf(float lo, float hi) {
    return (unsigned)f2bfu(lo) | ((unsigned)f2bfu(hi) << 16);
}
__device__ __forceinline__ float ulo(unsigned u) { return __uint_as_float(u << 16); }
__device__ __forceinline__ float uhi(unsigned u) { return __uint_as_float(u & 0xffff0000u); }

// 9-tap sliding sum over pv[0..10] -> 3 bf16 outputs into LDS
__device__ __forceinline__ void store3(unsigned short* wf16, int cidx, int row, int c0,
                                       const float* pv) {
    float s = 0.f;
#pragma unroll
    for (int k = 0; k < 9; ++k) s += pv[k];
    const float o1 = s - pv[0] + pv[9];
    const float o2 = o1 - pv[1] + pv[10];
    const int base = (cidx * RROW + row) * (2 * WSTR) + c0;
    wf16[base + 0] = f2bfu(s);
    wf16[base + 1] = f2bfu(o1);
    wf16[base + 2] = f2bfu(o2);
}

// ---------------- KA: W + H 9-tap (zero-padded) of the 5 product channels ----------------
__global__ __launch_bounds__(256) void ka_wh(const float* __restrict__ pred,
                                             const float* __restrict__ tgt,
                                             unsigned* __restrict__ BU) {
    const int b = blockIdx.x;              // d*24 + strip
    const int strip = b % NSTRIP;
    const int d = b / NSTRIP;
    const int h0 = strip * STRH;
    const size_t dbase = (size_t)d * S2;
    const int t = threadIdx.x;

    __shared__ unsigned IJ[RROW][RST];          // packed {i(lo), j(hi)} bf16 — 12.8 KB
    __shared__ unsigned wfU[NCH][RROW][WSTR];   // bf16x2 over w — 31.0 KB

    // zero the 4-col pads on both w-edges: cols 0..3 and 196..199 (one uint per col!)
    if (t < RROW * 8) {
        const int r = t >> 3, p = t & 7;
        const int col = (p < 4) ? p : (192 + p);   // 0..3 / 196..199
        IJ[r][col] = 0u;
    }
    // stage interior rows: float4 global loads -> packed bf16{i,j} uint4 LDS writes
    const float4* tg4 = (const float4*)tgt;
    const float4* pr4 = (const float4*)pred;
#pragma unroll
    for (int it = 0; it < 3; ++it) {
        const int u = t + 256 * it;            // 0..767
        const int r = u / 48, q = u % 48;
        const int hh = h0 - RAD + r;
        float4 vi = make_float4(0.f, 0.f, 0.f, 0.f), vj = vi;
        if (hh >= 0 && hh < SDIM) {
            const size_t gi = (dbase + (size_t)hh * SDIM) / 4 + q;
            vi = tg4[gi]; vj = pr4[gi];
        }
        uint4 w;
        w.x = packbf(vi.x, vj.x); w.y = packbf(vi.y, vj.y);
        w.z = packbf(vi.z, vj.z); w.w = packbf(vi.w, vj.w);
        *(uint4*)&IJ[r][4 + 4 * q] = w;
    }
    __syncthreads();

    // W phase: wave owns rows wv, wv+4, wv+8, wv+12; lane owns 3 consecutive output cols.
    unsigned short* wf16 = (unsigned short*)wfU;
    const int wv = t >> 6, lane = t & 63;
    const int c0 = lane * 3;
#pragma unroll
    for (int rr = 0; rr < 4; ++rr) {
        const int row = wv + rr * 4;
        float fi[11], fj[11];
#pragma unroll
        for (int k = 0; k < 11; ++k) {
            const unsigned u = IJ[row][c0 + k];
            fi[k] = ulo(u); fj[k] = uhi(u);
        }
        float pv[11];
#pragma unroll
        for (int k = 0; k < 11; ++k) pv[k] = fi[k];
        store3(wf16, 0, row, c0, pv);
#pragma unroll
        for (int k = 0; k < 11; ++k) pv[k] = fj[k];
        store3(wf16, 1, row, c0, pv);
#pragma unroll
        for (int k = 0; k < 11; ++k) pv[k] = fi[k] * fi[k];
        store3(wf16, 2, row, c0, pv);
#pragma unroll
        for (int k = 0; k < 11; ++k) pv[k] = fj[k] * fj[k];
        store3(wf16, 3, row, c0, pv);
#pragma unroll
        for (int k = 0; k < 11; ++k) pv[k] = fi[k] * fj[k];
        store3(wf16, 4, row, c0, pv);
    }
    __syncthreads();

    // H phase: thread owns a (channel, w-pair) column; sliding 9-sum over h, 8 outputs.
#pragma unroll
    for (int it = 0; it < 2; ++it) {
        const int col = t + 256 * it;          // 0..479 = c*96 + wp
        if (col < NCH * 96) {
            const int c = col / 96, wp = col % 96;
            float lo[RROW], hi[RROW];
#pragma unroll
            for (int r = 0; r < RROW; ++r) {
                const unsigned v = wfU[c][r][wp];
                lo[r] = ulo(v); hi[r] = uhi(v);
            }
            float slo = 0.f, shi = 0.f;
#pragma unroll
            for (int r = 0; r < 9; ++r) { slo += lo[r]; shi += hi[r]; }
            unsigned* dst = BU + (size_t)c * (S3 / 2) + (dbase + (size_t)h0 * SDIM) / 2 + wp;
            dst[0] = packbf(slo, shi);
#pragma unroll
            for (int hr = 1; hr < STRH; ++hr) {
                slo += lo[hr + 8] - lo[hr - 1];
                shi += hi[hr + 8] - hi[hr - 1];
                dst[hr * (SDIM / 2)] = packbf(slo, shi);
            }
        }
    }
}

// ---------------- KB: D-axis add/sub sliding window with uint4 loads + cc + reduce ----------------
#define SLICE4(s, OP) { const size_t sb = ((size_t)(s) * S2 + pos0) >> 3; \
    _Pragma("unroll") for (int c = 0; c < NCH; ++c) { \
        const uint4 v = B4[(size_t)c * (S3 >> 3) + sb]; \
        z[c][0] OP ulo(v.x); z[c][1] OP uhi(v.x); \
        z[c][2] OP ulo(v.y); z[c][3] OP uhi(v.y); \
        z[c][4] OP ulo(v.z); z[c][5] OP uhi(v.z); \
        z[c][6] OP ulo(v.w); z[c][7] OP uhi(v.w); } }

__global__ __launch_bounds__(256) void kb_d_cc(const unsigned* __restrict__ BU,
                                               float* __restrict__ partials) {
    const int bid = blockIdx.x;
    const int dc = bid / KB_POSB;
    const int pb = bid % KB_POSB;
    const int d0 = dc * KB_DCH;
    const int pos0 = pb * (256 * KB_KBC) + threadIdx.x * KB_KBC;
    const uint4* B4 = (const uint4*)BU;

    float z[NCH][KB_KBC];
#pragma unroll
    for (int c = 0; c < NCH; ++c)
#pragma unroll
        for (int i = 0; i < KB_KBC; ++i) z[c][i] = 0.f;

    // warm up: window for output d0 (slices d0-4..d0+4, zero-padded)
#pragma unroll
    for (int dd = -RAD; dd <= RAD; ++dd) {
        const int s = d0 + dd;
        if (s >= 0 && s < SDIM) SLICE4(s, +=)
    }

    const float inv = 1.0f / 729.0f;
    const float eps = 1.1920929e-07f;      // np.finfo(float32).eps
    float acc = 0.f;

#pragma unroll
    for (int k = 0; k < KB_DCH; ++k) {
        const int d = d0 + k;
#pragma unroll
        for (int i = 0; i < KB_KBC; ++i) {
            const float mu1 = z[0][i] * inv;
            const float mu2 = z[1][i] * inv;
            const float sg1 = z[2][i] * inv - mu1 * mu1;
            const float sg2 = z[3][i] * inv - mu2 * mu2;
            const float s12 = z[4][i] * inv - mu1 * mu2;
            acc += (s12 * s12) / (sg1 * sg2 + eps);
        }
        const int da = d + RAD + 1;
        const int ds = d - RAD;
        if (da < SDIM) SLICE4(da, +=)
        if (ds >= 0)   SLICE4(ds, -=)
    }

    __shared__ float red[256];
    red[threadIdx.x] = acc;
    __syncthreads();
#pragma unroll
    for (int o = 128; o > 0; o >>= 1) {
        if (threadIdx.x < o) red[threadIdx.x] += red[threadIdx.x + o];
        __syncthreads();
    }
    if (threadIdx.x == 0) partials[bid] = red[0];
}

// ---------------- K4: final deterministic reduction ----------------
__global__ __launch_bounds__(256) void k4_finalize(const float* __restrict__ partials,
                                                   float* __restrict__ out) {
    __shared__ float sm[256];
    float s = 0.f;
    for (int i = threadIdx.x; i < NPART; i += 256) s += partials[i];
    sm[threadIdx.x] = s;
    __syncthreads();
#pragma unroll
    for (int o = 128; o > 0; o >>= 1) {
        if (threadIdx.x < o) sm[threadIdx.x] += sm[threadIdx.x + o];
        __syncthreads();
    }
    if (threadIdx.x == 0) out[0] = 1.0f - sm[0] / (float)((size_t)SDIM * S2);
}

extern "C" void kernel_launch(void* const* d_in, const int* in_sizes, int n_in,
                              void* d_out, int out_size, void* d_ws, size_t ws_size,
                              hipStream_t stream) {
    const float* pred = (const float*)d_in[0];
    const float* tgt  = (const float*)d_in[1];
    float* out = (float*)d_out;

    const size_t b_bytes = (size_t)NCH * S3 * sizeof(__hip_bfloat16);   // ~70.8 MB
    const size_t b_pad = (b_bytes + 255) & ~(size_t)255;

    unsigned* BU = (unsigned*)d_ws;
    float* partials = (float*)((char*)d_ws + b_pad);

    ka_wh<<<SDIM * NSTRIP, 256, 0, stream>>>(pred, tgt, BU);
    kb_d_cc<<<KB_GRID, 256, 0, stream>>>(BU, partials);
    k4_finalize<<<1, 256, 0, stream>>>(partials, out);
}